// Round 1
// baseline (3876.762 us; speedup 1.0000x reference)
//
#include <hip/hip_runtime.h>
#include <math.h>

#define NTOK 64
#define DIMF 128
#define NHEAD 4
#define HDIM 32
#define NWMASK 192

// LDS float-offsets (total = 16384 floats = 65536 B exactly)
//   XC : [64][36]              = 2304 floats   (x K-chunk)
//   WC : [128][36]             = 4608 floats   (weight K-chunk)  UNION att [64][65]=4160
//   HB : 4 x [64][37]          = 9472 floats   (q,k,q2,k2; v->HB[0] pitch36; wv->HB+HBP;
//                                               phase-B: os [64][132]=8448)
#define XC  0
#define WC  2304
#define ATT 2304
#define HB  6912
#define HBP 2368
#define OS  6912

__device__ __forceinline__ float dot4(float4 a, float4 b) {
  return a.x*b.x + a.y*b.y + a.z*b.z + a.w*b.w;
}

__global__ void pb_kernel(const float* __restrict__ Wp1, const float* __restrict__ bp1,
                          const float* __restrict__ Wp2, const float* __restrict__ bp2,
                          float* __restrict__ pb) {
  int idx = blockIdx.x * 256 + threadIdx.x;     // (i,j) pair, 4096 total
  if (idx >= 4096) return;
  int i = idx >> 6, j = idx & 63;
  float dx = (float)((i & 7) - (j & 7));        // xi - xj
  float dy = -(float)((i >> 3) - (j >> 3));     // -(yi - yj)
  float r = sqrtf(dx*dx + dy*dy + 1e-9f);
  float theta = atan2f(dx, dy);
  float p0 = r * (1.0f / 9.899494936611665f);               // / sqrt(98)
  float p1 = (theta + 3.14159265358979323846f) * (1.0f / 6.283185307179586f);
  float a0 = 0.f, a1 = 0.f, a2 = 0.f, a3 = 0.f;
  for (int f = 0; f < 64; ++f) {
    float hpre = p0 * Wp1[2*f] + p1 * Wp1[2*f+1] + bp1[f];
    float g = 0.5f * hpre * (1.0f + erff(hpre * 0.70710678118654752f)); // exact GELU
    a0 += Wp2[f]       * g;
    a1 += Wp2[64 + f]  * g;
    a2 += Wp2[128 + f] * g;
    a3 += Wp2[192 + f] * g;
  }
  pb[idx]          = a0 + bp2[0];
  pb[4096 + idx]   = a1 + bp2[1];
  pb[8192 + idx]   = a2 + bp2[2];
  pb[12288 + idx]  = a3 + bp2[3];
}

__global__ __launch_bounds__(256, 2)
void fused_attn(const float* __restrict__ x, const float* __restrict__ mask,
                const float* __restrict__ Wqkv, const float* __restrict__ bqkv,
                const float* __restrict__ Wqkv2, const float* __restrict__ bqkv2,
                const float* __restrict__ lq1, const float* __restrict__ lk1,
                const float* __restrict__ lq2, const float* __restrict__ lk2,
                const float* __restrict__ subln,
                const float* __restrict__ Wproj, const float* __restrict__ bproj,
                const float* __restrict__ pb, float* __restrict__ out) {
  __shared__ float smem[16384];

  const int b = blockIdx.x;
  const int t = threadIdx.x;
  const int tg  = t >> 4;  // 0..15  (stage1a / stage2 rows / proj)
  const int cg  = t & 15;  // 0..15
  const int tg2 = t >> 3;  // 0..31  (stage1b / stage3)
  const int cg2 = t & 7;   // 0..7
  const int sr  = t >> 2;  // 0..63  (softmax row)
  const int sq  = t & 3;   // 0..3

  const float* xg    = x + (size_t)b * (NTOK * DIMF);
  const float* maskw = mask + (size_t)(b % NWMASK) * (NTOK * NTOK);

  float lam;
  {
    float s1 = 0.f, s2 = 0.f;
#pragma unroll
    for (int i = 0; i < 16; ++i) { s1 += lq1[i]*lk1[i]; s2 += lq2[i]*lk2[i]; }
    lam = expf(s1) - expf(s2) + 0.2f;   // LAMBDA_INIT = 0.2
  }

  float4 o_all[NHEAD][2];

  for (int h = 0; h < NHEAD; ++h) {
    // ===== stage 1a: q,k,q2,k2 = x @ W^T (K-chunked through LDS) =====
    float acc[4][8];
#pragma unroll
    for (int i = 0; i < 4; ++i)
#pragma unroll
      for (int j = 0; j < 8; ++j) acc[i][j] = 0.f;

    for (int kc = 0; kc < DIMF; kc += 32) {
      __syncthreads();
#pragma unroll
      for (int u = 0; u < 2; ++u) {
        int f = t + u*256;
        int n = f >> 3, seg = f & 7;
        *(float4*)(&smem[XC + n*36 + seg*4]) =
            *(const float4*)(xg + n*DIMF + kc + seg*4);
      }
#pragma unroll
      for (int u = 0; u < 4; ++u) {
        int f = t + u*256;
        int c = f >> 3, seg = f & 7;      // c: 0..127 -> mat = c/32 (q,k,q2,k2)
        int mat = c >> 5, r = c & 31;
        const float* src = (mat == 0) ? (Wqkv  + (h*HDIM + r)*DIMF)
                         : (mat == 1) ? (Wqkv  + (DIMF + h*HDIM + r)*DIMF)
                         : (mat == 2) ? (Wqkv2 + (h*HDIM + r)*DIMF)
                                      : (Wqkv2 + (DIMF + h*HDIM + r)*DIMF);
        *(float4*)(&smem[WC + c*36 + seg*4]) = *(const float4*)(src + kc + seg*4);
      }
      __syncthreads();
#pragma unroll
      for (int k4 = 0; k4 < 8; ++k4) {
        float4 xv[4];
#pragma unroll
        for (int i = 0; i < 4; ++i)
          xv[i] = *(const float4*)(&smem[XC + (4*tg + i)*36 + k4*4]);
#pragma unroll
        for (int j = 0; j < 8; ++j) {
          float4 wv = *(const float4*)(&smem[WC + (cg + 16*j)*36 + k4*4]);
#pragma unroll
          for (int i = 0; i < 4; ++i) acc[i][j] += dot4(xv[i], wv);
        }
      }
    }
    __syncthreads();
    // bias + scale, store to HB (pitch 37)
#pragma unroll
    for (int j = 0; j < 8; ++j) {
      int mat = j >> 1;                   // 0:q 1:k 2:q2 3:k2
      int r = ((j & 1) << 4) + cg;        // 0..31
      float bias = (mat == 0) ? bqkv[h*HDIM + r]
                 : (mat == 1) ? bqkv[DIMF + h*HDIM + r]
                 : (mat == 2) ? bqkv2[h*HDIM + r]
                              : bqkv2[DIMF + h*HDIM + r];
      float sc = (mat == 0 || mat == 2) ? 0.17677669529663687f : 1.0f;  // HD^-0.5
#pragma unroll
      for (int i = 0; i < 4; ++i)
        smem[HB + mat*HBP + (4*tg + i)*37 + r] = (acc[i][j] + bias) * sc;
    }
    __syncthreads();

    // ===== stage 2: logits s1 - lam*s2 + pb + mask -> att =====
    {
      float s1a[4][4], s2a[4][4];
#pragma unroll
      for (int i = 0; i < 4; ++i)
#pragma unroll
        for (int j = 0; j < 4; ++j) { s1a[i][j] = 0.f; s2a[i][j] = 0.f; }
      for (int kk = 0; kk < HDIM; ++kk) {
        float qv[4], kv[4], q2v[4], k2v[4];
#pragma unroll
        for (int i = 0; i < 4; ++i) {
          qv[i]  = smem[HB + 0*HBP + (4*tg + i)*37 + kk];
          q2v[i] = smem[HB + 2*HBP + (4*tg + i)*37 + kk];
          kv[i]  = smem[HB + 1*HBP + (4*cg + i)*37 + kk];
          k2v[i] = smem[HB + 3*HBP + (4*cg + i)*37 + kk];
        }
#pragma unroll
        for (int i = 0; i < 4; ++i)
#pragma unroll
          for (int j = 0; j < 4; ++j) {
            s1a[i][j] += qv[i]*kv[j];
            s2a[i][j] += q2v[i]*k2v[j];
          }
      }
#pragma unroll
      for (int i = 0; i < 4; ++i) {
        int iw = 4*tg + i;
        float4 pb4 = *(const float4*)(pb + h*4096 + iw*64 + 4*cg);
        float4 m4  = *(const float4*)(maskw + iw*64 + 4*cg);
        smem[ATT + iw*65 + 4*cg + 0] = s1a[i][0] - lam*s2a[i][0] + pb4.x + m4.x;
        smem[ATT + iw*65 + 4*cg + 1] = s1a[i][1] - lam*s2a[i][1] + pb4.y + m4.y;
        smem[ATT + iw*65 + 4*cg + 2] = s1a[i][2] - lam*s2a[i][2] + pb4.z + m4.z;
        smem[ATT + iw*65 + 4*cg + 3] = s1a[i][3] - lam*s2a[i][3] + pb4.w + m4.w;
      }
    }
    __syncthreads();

    // ===== softmax (4 lanes per row, shfl combine) =====
    {
      float e[16];
      float mx = -3.0e38f;
#pragma unroll
      for (int jj = 0; jj < 16; ++jj) {
        e[jj] = smem[ATT + sr*65 + sq*16 + jj];
        mx = fmaxf(mx, e[jj]);
      }
      mx = fmaxf(mx, __shfl_xor(mx, 1));
      mx = fmaxf(mx, __shfl_xor(mx, 2));
      float sum = 0.f;
#pragma unroll
      for (int jj = 0; jj < 16; ++jj) { e[jj] = __expf(e[jj] - mx); sum += e[jj]; }
      sum += __shfl_xor(sum, 1);
      sum += __shfl_xor(sum, 2);
      float inv = 1.0f / sum;
#pragma unroll
      for (int jj = 0; jj < 16; ++jj)
        smem[ATT + sr*65 + sq*16 + jj] = e[jj] * inv;
    }

    // ===== stage 1b: v = x @ Wv^T (q/k buffers now dead; wv chunk -> HB+HBP) =====
    float vacc[2][4];
#pragma unroll
    for (int i = 0; i < 2; ++i)
#pragma unroll
      for (int j = 0; j < 4; ++j) vacc[i][j] = 0.f;
    for (int kc = 0; kc < DIMF; kc += 32) {
      __syncthreads();
#pragma unroll
      for (int u = 0; u < 2; ++u) {
        int f = t + u*256;
        int n = f >> 3, seg = f & 7;
        *(float4*)(&smem[XC + n*36 + seg*4]) =
            *(const float4*)(xg + n*DIMF + kc + seg*4);
      }
      {
        int c = t >> 3, seg = t & 7;     // 32 rows x 8 segs = 256 loads
        const float* src = Wqkv + (2*DIMF + h*HDIM + c)*DIMF;
        *(float4*)(&smem[HB + HBP + c*36 + seg*4]) = *(const float4*)(src + kc + seg*4);
      }
      __syncthreads();
#pragma unroll
      for (int k4 = 0; k4 < 8; ++k4) {
        float4 xv[2];
#pragma unroll
        for (int i = 0; i < 2; ++i)
          xv[i] = *(const float4*)(&smem[XC + (2*tg2 + i)*36 + k4*4]);
#pragma unroll
        for (int j = 0; j < 4; ++j) {
          float4 wv = *(const float4*)(&smem[HB + HBP + (4*cg2 + j)*36 + k4*4]);
#pragma unroll
          for (int i = 0; i < 2; ++i) vacc[i][j] += dot4(xv[i], wv);
        }
      }
    }
    __syncthreads();
#pragma unroll
    for (int i = 0; i < 2; ++i)
#pragma unroll
      for (int j = 0; j < 4; ++j)
        smem[HB + (2*tg2 + i)*36 + 4*cg2 + j] =
            vacc[i][j] + bqkv[2*DIMF + h*HDIM + 4*cg2 + j];
    __syncthreads();

    // ===== stage 3: o = att @ v, then RMSNorm in registers =====
    {
      float oa[2][4];
#pragma unroll
      for (int i = 0; i < 2; ++i)
#pragma unroll
        for (int j = 0; j < 4; ++j) oa[i][j] = 0.f;
      for (int kk = 0; kk < NTOK; ++kk) {
        float p0 = smem[ATT + (2*tg2 + 0)*65 + kk];
        float p1 = smem[ATT + (2*tg2 + 1)*65 + kk];
        float4 vv = *(const float4*)(&smem[HB + kk*36 + 4*cg2]);
        oa[0][0] += p0*vv.x; oa[0][1] += p0*vv.y; oa[0][2] += p0*vv.z; oa[0][3] += p0*vv.w;
        oa[1][0] += p1*vv.x; oa[1][1] += p1*vv.y; oa[1][2] += p1*vv.z; oa[1][3] += p1*vv.w;
      }
      float ss0 = oa[0][0]*oa[0][0] + oa[0][1]*oa[0][1] + oa[0][2]*oa[0][2] + oa[0][3]*oa[0][3];
      float ss1 = oa[1][0]*oa[1][0] + oa[1][1]*oa[1][1] + oa[1][2]*oa[1][2] + oa[1][3]*oa[1][3];
      ss0 += __shfl_xor(ss0, 1); ss0 += __shfl_xor(ss0, 2); ss0 += __shfl_xor(ss0, 4);
      ss1 += __shfl_xor(ss1, 1); ss1 += __shfl_xor(ss1, 2); ss1 += __shfl_xor(ss1, 4);
      float rs0 = 1.0f / sqrtf(ss0 * (1.0f/32.0f) + 1e-9f);
      float rs1 = 1.0f / sqrtf(ss1 * (1.0f/32.0f) + 1e-9f);
      float w0 = subln[4*cg2 + 0] * 0.8f;   // * (1 - LAMBDA_INIT)
      float w1 = subln[4*cg2 + 1] * 0.8f;
      float w2 = subln[4*cg2 + 2] * 0.8f;
      float w3 = subln[4*cg2 + 3] * 0.8f;
      o_all[h][0] = make_float4(oa[0][0]*rs0*w0, oa[0][1]*rs0*w1, oa[0][2]*rs0*w2, oa[0][3]*rs0*w3);
      o_all[h][1] = make_float4(oa[1][0]*rs1*w0, oa[1][1]*rs1*w1, oa[1][2]*rs1*w2, oa[1][3]*rs1*w3);
    }
    // next head's first __syncthreads() (in the kc loop) fences att/v reuse
  }

  // ===== phase B: out = os @ Wproj^T + bproj =====
  __syncthreads();
#pragma unroll
  for (int h = 0; h < NHEAD; ++h)
#pragma unroll
    for (int i = 0; i < 2; ++i)
      *(float4*)(&smem[OS + (2*tg2 + i)*132 + h*HDIM + 4*cg2]) = o_all[h][i];

  float acc4[4][8];
#pragma unroll
  for (int i = 0; i < 4; ++i)
#pragma unroll
    for (int j = 0; j < 8; ++j) acc4[i][j] = 0.f;
  for (int kc = 0; kc < DIMF; kc += 32) {
    __syncthreads();
#pragma unroll
    for (int u = 0; u < 4; ++u) {
      int f = t + u*256;
      int d = f >> 3, seg = f & 7;
      *(float4*)(&smem[WC + d*36 + seg*4]) =
          *(const float4*)(Wproj + d*DIMF + kc + seg*4);
    }
    __syncthreads();
#pragma unroll
    for (int k4 = 0; k4 < 8; ++k4) {
      float4 ov[4];
#pragma unroll
      for (int i = 0; i < 4; ++i)
        ov[i] = *(const float4*)(&smem[OS + (4*tg + i)*132 + kc + k4*4]);
#pragma unroll
      for (int j = 0; j < 8; ++j) {
        float4 wv = *(const float4*)(&smem[WC + (cg + 16*j)*36 + k4*4]);
#pragma unroll
        for (int i = 0; i < 4; ++i) acc4[i][j] += dot4(ov[i], wv);
      }
    }
  }
  float* og = out + (size_t)b * (NTOK * DIMF);
#pragma unroll
  for (int j = 0; j < 8; ++j) {
    int d = cg + 16*j;
    float bp = bproj[d];
#pragma unroll
    for (int i = 0; i < 4; ++i)
      og[(4*tg + i)*DIMF + d] = acc4[i][j] + bp;
  }
}

extern "C" void kernel_launch(void* const* d_in, const int* in_sizes, int n_in,
                              void* d_out, int out_size, void* d_ws, size_t ws_size,
                              hipStream_t stream) {
  (void)in_sizes; (void)n_in; (void)out_size; (void)ws_size;
  const float* x     = (const float*)d_in[0];
  const float* mask  = (const float*)d_in[1];
  const float* Wqkv  = (const float*)d_in[2];
  const float* bqkv  = (const float*)d_in[3];
  const float* Wqkv2 = (const float*)d_in[4];
  const float* bqkv2 = (const float*)d_in[5];
  const float* Wp1   = (const float*)d_in[6];
  const float* bp1   = (const float*)d_in[7];
  const float* Wp2   = (const float*)d_in[8];
  const float* bp2   = (const float*)d_in[9];
  const float* lq1   = (const float*)d_in[10];
  const float* lk1   = (const float*)d_in[11];
  const float* lq2   = (const float*)d_in[12];
  const float* lk2   = (const float*)d_in[13];
  const float* subln = (const float*)d_in[14];
  const float* Wproj = (const float*)d_in[15];
  const float* bproj = (const float*)d_in[16];
  float* out = (float*)d_out;
  float* pb  = (float*)d_ws;   // 16384 floats = 64 KB

  hipLaunchKernelGGL(pb_kernel, dim3(16), dim3(256), 0, stream,
                     Wp1, bp1, Wp2, bp2, pb);
  hipLaunchKernelGGL(fused_attn, dim3(3072), dim3(256), 0, stream,
                     x, mask, Wqkv, bqkv, Wqkv2, bqkv2,
                     lq1, lk1, lq2, lk2, subln, Wproj, bproj, pb, out);
}

// Round 2
// 417.638 us; speedup vs baseline: 9.2826x; 9.2826x over previous
//
#include <hip/hip_runtime.h>
#include <math.h>

typedef __attribute__((ext_vector_type(8))) short bf16x8;
typedef __attribute__((ext_vector_type(4))) float f32x4;

#define NTOK 64
#define NWMASK 192

__device__ __forceinline__ unsigned short f2bf(float f) {
  union { float f; unsigned u; } v; v.f = f;
  return (unsigned short)((v.u + 0x7fffu + ((v.u >> 16) & 1u)) >> 16);
}

// ---------------- polar position bias (once, tiny) ----------------
__global__ void pb_kernel(const float* __restrict__ Wp1, const float* __restrict__ bp1,
                          const float* __restrict__ Wp2, const float* __restrict__ bp2,
                          float* __restrict__ pb) {
  int idx = blockIdx.x * 256 + threadIdx.x;     // (i,j) pair, 4096 total
  if (idx >= 4096) return;
  int i = idx >> 6, j = idx & 63;
  float dx = (float)((i & 7) - (j & 7));
  float dy = -(float)((i >> 3) - (j >> 3));
  float r = sqrtf(dx*dx + dy*dy + 1e-9f);
  float theta = atan2f(dx, dy);
  float p0 = r * (1.0f / 9.899494936611665f);
  float p1 = (theta + 3.14159265358979323846f) * (1.0f / 6.283185307179586f);
  float a0 = 0.f, a1 = 0.f, a2 = 0.f, a3 = 0.f;
  for (int f = 0; f < 64; ++f) {
    float hpre = p0 * Wp1[2*f] + p1 * Wp1[2*f+1] + bp1[f];
    float g = 0.5f * hpre * (1.0f + erff(hpre * 0.70710678118654752f));
    a0 += Wp2[f]       * g;
    a1 += Wp2[64 + f]  * g;
    a2 += Wp2[128 + f] * g;
    a3 += Wp2[192 + f] * g;
  }
  pb[idx]          = a0 + bp2[0];
  pb[4096 + idx]   = a1 + bp2[1];
  pb[8192 + idx]   = a2 + bp2[2];
  pb[12288 + idx]  = a3 + bp2[3];
}

// ---------------- K1: qkv + qk2 projection (bf16 MFMA) ----------------
// C[196608 x 640] = X[196608 x 128] @ W~^T ; W~ rows: [q|k|v](Wqkv) ++ [q2|k2](Wqkv2)
// out: qkv[b][mat(5)][h(4)][tok(64)][d(32)] bf16, q/q2 pre-scaled by HD^-0.5
__global__ __launch_bounds__(256, 2)
void qkv_proj(const float* __restrict__ x,
              const float* __restrict__ Wqkv, const float* __restrict__ bqkv,
              const float* __restrict__ Wqkv2, const float* __restrict__ bqkv2,
              unsigned short* __restrict__ qkv) {
  __shared__ unsigned short Xl[128 * 128];   // [row][16B-unit ^ (row&7)]
  __shared__ unsigned short Wl[128 * 128];

  const int t = threadIdx.x;
  const int w = t >> 6;
  const int lane = t & 63;
  const int m = lane & 15;
  const int quad = lane >> 4;
  const int tau0 = blockIdx.x * 128;

  // stage X (fp32 -> bf16, XOR-swizzled 16B units)
#pragma unroll
  for (int u = 0; u < 8; ++u) {
    int id = u * 256 + t;
    int r = id >> 4, c16 = id & 15;
    const float* src = x + (size_t)(tau0 + r) * 128 + c16 * 8;
    float4 lo = *(const float4*)(src);
    float4 hi = *(const float4*)(src + 4);
    bf16x8 pk;
    pk[0] = (short)f2bf(lo.x); pk[1] = (short)f2bf(lo.y);
    pk[2] = (short)f2bf(lo.z); pk[3] = (short)f2bf(lo.w);
    pk[4] = (short)f2bf(hi.x); pk[5] = (short)f2bf(hi.y);
    pk[6] = (short)f2bf(hi.z); pk[7] = (short)f2bf(hi.w);
    *(bf16x8*)(&Xl[r * 128 + (c16 ^ (r & 7)) * 8]) = pk;
  }

  auto stageW = [&](int nblk) {
#pragma unroll
    for (int u = 0; u < 8; ++u) {
      int id = u * 256 + t;
      int r = id >> 4, c16 = id & 15;
      const float* src = (nblk < 3)
          ? (Wqkv + (size_t)(nblk * 128 + r) * 128 + c16 * 8)
          : (Wqkv2 + (size_t)((nblk - 3) * 128 + r) * 128 + c16 * 8);
      float4 lo = *(const float4*)(src);
      float4 hi = *(const float4*)(src + 4);
      bf16x8 pk;
      pk[0] = (short)f2bf(lo.x); pk[1] = (short)f2bf(lo.y);
      pk[2] = (short)f2bf(lo.z); pk[3] = (short)f2bf(lo.w);
      pk[4] = (short)f2bf(hi.x); pk[5] = (short)f2bf(hi.y);
      pk[6] = (short)f2bf(hi.z); pk[7] = (short)f2bf(hi.w);
      *(bf16x8*)(&Wl[r * 128 + (c16 ^ (r & 7)) * 8]) = pk;
    }
  };
  stageW(0);

  for (int nblk = 0; nblk < 5; ++nblk) {
    __syncthreads();   // staged X/W visible
    f32x4 acc[4][4];
#pragma unroll
    for (int mi = 0; mi < 4; ++mi)
#pragma unroll
      for (int ni = 0; ni < 4; ++ni) acc[mi][ni] = (f32x4){0.f, 0.f, 0.f, 0.f};

#pragma unroll
    for (int ks = 0; ks < 4; ++ks) {
      bf16x8 af[4], bfr[4];
      int unit = (ks * 4 + quad) ^ (m & 7);
#pragma unroll
      for (int mi = 0; mi < 4; ++mi) {
        int row = (w & 1) * 64 + mi * 16 + m;
        af[mi] = *(const bf16x8*)(&Xl[row * 128 + unit * 8]);
      }
#pragma unroll
      for (int ni = 0; ni < 4; ++ni) {
        int row = (w >> 1) * 64 + ni * 16 + m;
        bfr[ni] = *(const bf16x8*)(&Wl[row * 128 + unit * 8]);
      }
#pragma unroll
      for (int mi = 0; mi < 4; ++mi)
#pragma unroll
        for (int ni = 0; ni < 4; ++ni)
          acc[mi][ni] = __builtin_amdgcn_mfma_f32_16x16x32_bf16(
              af[mi], bfr[ni], acc[mi][ni], 0, 0, 0);
    }
    __syncthreads();   // all waves done reading Wl
    if (nblk < 4) stageW(nblk + 1);

    // epilogue: (acc + bias) * scale -> bf16 -> qkv[b][mat][h][tok][d]
    const float scale = (nblk == 0 || nblk == 3) ? 0.17677669529663687f : 1.0f;
#pragma unroll
    for (int ni = 0; ni < 4; ++ni) {
      int f7 = (w >> 1) * 64 + ni * 16 + m;         // 0..127 within mat
      int fg = nblk * 128 + f7;
      float bias = (fg < 384) ? bqkv[fg] : bqkv2[fg - 384];
      int hh = f7 >> 5, d = f7 & 31;
#pragma unroll
      for (int mi = 0; mi < 4; ++mi) {
        int trow = tau0 + (w & 1) * 64 + mi * 16 + quad * 4;
#pragma unroll
        for (int reg = 0; reg < 4; ++reg) {
          int tau = trow + reg;
          int b = tau >> 6, tok = tau & 63;
          size_t dst = ((size_t)(b * 5 + nblk) * 4 + hh) * 2048 + tok * 32 + d;
          qkv[dst] = f2bf((acc[mi][ni][reg] + bias) * scale);
        }
      }
    }
  }
}

// ---------------- K2: attention core, one wave per head ----------------
__global__ __launch_bounds__(256, 2)
void attn_core(const unsigned short* __restrict__ qkv,
               const float* __restrict__ mask, const float* __restrict__ pb,
               const float* __restrict__ lq1, const float* __restrict__ lk1,
               const float* __restrict__ lq2, const float* __restrict__ lk2,
               const float* __restrict__ subln,
               unsigned short* __restrict__ obuf) {
  __shared__ unsigned short Pl[4][64 * 72];   // per-head P (bf16), pitch 72

  const int b = blockIdx.x;
  const int t = threadIdx.x;
  const int h = t >> 6;
  const int lane = t & 63;
  const int n15 = lane & 15, quad = lane >> 4;

  float lam;
  {
    float s1 = 0.f, s2 = 0.f;
#pragma unroll
    for (int i = 0; i < 16; ++i) { s1 += lq1[i] * lk1[i]; s2 += lq2[i] * lk2[i]; }
    lam = expf(s1) - expf(s2) + 0.2f;
  }

  const unsigned short* base = qkv + ((size_t)b * 5 * 4 + h) * 2048;
  // mats strided by 4*2048 = 8192 elems: 0=q 1=k 2=v 3=q2 4=k2
  bf16x8 qf[4], kf[4], q2f[4], k2f[4];
#pragma unroll
  for (int i = 0; i < 4; ++i) {
    size_t off = (size_t)(i * 16 + n15) * 32 + quad * 8;
    qf[i]  = *(const bf16x8*)(base + 0 * 8192 + off);
    kf[i]  = *(const bf16x8*)(base + 1 * 8192 + off);
    q2f[i] = *(const bf16x8*)(base + 3 * 8192 + off);
    k2f[i] = *(const bf16x8*)(base + 4 * 8192 + off);
  }

  const float* pbh = pb + h * 4096;
  const float* mk = mask + (size_t)(b % NWMASK) * 4096;
  const f32x4 zero4 = (f32x4){0.f, 0.f, 0.f, 0.f};

  f32x4 S[4][4];
#pragma unroll
  for (int mi = 0; mi < 4; ++mi)
#pragma unroll
    for (int ni = 0; ni < 4; ++ni) {
      f32x4 c;
#pragma unroll
      for (int reg = 0; reg < 4; ++reg) {
        int row = mi * 16 + quad * 4 + reg, col = ni * 16 + n15;
        c[reg] = pbh[row * 64 + col] + mk[row * 64 + col];
      }
      f32x4 t2 = __builtin_amdgcn_mfma_f32_16x16x32_bf16(q2f[mi], k2f[ni], zero4, 0, 0, 0);
      f32x4 s = __builtin_amdgcn_mfma_f32_16x16x32_bf16(qf[mi], kf[ni], c, 0, 0, 0);
#pragma unroll
      for (int reg = 0; reg < 4; ++reg) s[reg] -= lam * t2[reg];
      S[mi][ni] = s;
    }

  // softmax: row = mi*16 + quad*4 + reg; 64 cols = 4 ni-tiles x 16 lanes
#pragma unroll
  for (int mi = 0; mi < 4; ++mi) {
#pragma unroll
    for (int reg = 0; reg < 4; ++reg) {
      float mx = fmaxf(fmaxf(S[mi][0][reg], S[mi][1][reg]),
                       fmaxf(S[mi][2][reg], S[mi][3][reg]));
      mx = fmaxf(mx, __shfl_xor(mx, 1));
      mx = fmaxf(mx, __shfl_xor(mx, 2));
      mx = fmaxf(mx, __shfl_xor(mx, 4));
      mx = fmaxf(mx, __shfl_xor(mx, 8));
      float e0 = __expf(S[mi][0][reg] - mx);
      float e1 = __expf(S[mi][1][reg] - mx);
      float e2 = __expf(S[mi][2][reg] - mx);
      float e3 = __expf(S[mi][3][reg] - mx);
      float sum = e0 + e1 + e2 + e3;
      sum += __shfl_xor(sum, 1);
      sum += __shfl_xor(sum, 2);
      sum += __shfl_xor(sum, 4);
      sum += __shfl_xor(sum, 8);
      float inv = 1.0f / sum;
      int row = mi * 16 + quad * 4 + reg;
      Pl[h][row * 72 +  0 + n15] = f2bf(e0 * inv);
      Pl[h][row * 72 + 16 + n15] = f2bf(e1 * inv);
      Pl[h][row * 72 + 32 + n15] = f2bf(e2 * inv);
      Pl[h][row * 72 + 48 + n15] = f2bf(e3 * inv);
    }
  }
  __syncthreads();

  // V fragments: B[k=token][n=d]
  const unsigned short* vsrc = base + 2 * 8192;
  bf16x8 vb[2][2];
#pragma unroll
  for (int nd = 0; nd < 2; ++nd)
#pragma unroll
    for (int kc = 0; kc < 2; ++kc) {
#pragma unroll
      for (int j = 0; j < 8; ++j)
        vb[nd][kc][j] = (short)vsrc[(kc * 32 + quad * 8 + j) * 32 + nd * 16 + n15];
    }

  f32x4 O[4][2];
#pragma unroll
  for (int mi = 0; mi < 4; ++mi) {
    O[mi][0] = zero4; O[mi][1] = zero4;
#pragma unroll
    for (int kc = 0; kc < 2; ++kc) {
      bf16x8 pa = *(const bf16x8*)(&Pl[h][(mi * 16 + n15) * 72 + kc * 32 + quad * 8]);
      O[mi][0] = __builtin_amdgcn_mfma_f32_16x16x32_bf16(pa, vb[0][kc], O[mi][0], 0, 0, 0);
      O[mi][1] = __builtin_amdgcn_mfma_f32_16x16x32_bf16(pa, vb[1][kc], O[mi][1], 0, 0, 0);
    }
  }

  // RMSNorm per row, scale, store bf16 to obuf[b][tok][h*32+d]
  float w0 = subln[n15] * 0.8f;
  float w1 = subln[16 + n15] * 0.8f;
#pragma unroll
  for (int mi = 0; mi < 4; ++mi) {
#pragma unroll
    for (int reg = 0; reg < 4; ++reg) {
      float a0 = O[mi][0][reg], a1 = O[mi][1][reg];
      float ss = a0 * a0 + a1 * a1;
      ss += __shfl_xor(ss, 1);
      ss += __shfl_xor(ss, 2);
      ss += __shfl_xor(ss, 4);
      ss += __shfl_xor(ss, 8);
      float rs = 1.0f / sqrtf(ss * (1.0f / 32.0f) + 1e-9f);
      int row = mi * 16 + quad * 4 + reg;
      size_t o0 = ((size_t)b * 64 + row) * 128 + h * 32;
      obuf[o0 + n15]      = f2bf(a0 * rs * w0);
      obuf[o0 + 16 + n15] = f2bf(a1 * rs * w1);
    }
  }
}

// ---------------- K3: output projection (bf16 MFMA, fp32 out) ----------------
__global__ __launch_bounds__(256, 2)
void out_proj(const unsigned short* __restrict__ obuf,
              const float* __restrict__ Wproj, const float* __restrict__ bproj,
              float* __restrict__ out) {
  __shared__ unsigned short Al[128 * 128];
  __shared__ unsigned short Wl[128 * 128];

  const int t = threadIdx.x;
  const int w = t >> 6;
  const int lane = t & 63;
  const int m = lane & 15;
  const int quad = lane >> 4;
  const int tau0 = blockIdx.x * 128;

#pragma unroll
  for (int u = 0; u < 8; ++u) {
    int id = u * 256 + t;
    int r = id >> 4, c16 = id & 15;
    bf16x8 v = *(const bf16x8*)(obuf + (size_t)(tau0 + r) * 128 + c16 * 8);
    *(bf16x8*)(&Al[r * 128 + (c16 ^ (r & 7)) * 8]) = v;
  }
#pragma unroll
  for (int u = 0; u < 8; ++u) {
    int id = u * 256 + t;
    int r = id >> 4, c16 = id & 15;
    const float* src = Wproj + (size_t)r * 128 + c16 * 8;
    float4 lo = *(const float4*)(src);
    float4 hi = *(const float4*)(src + 4);
    bf16x8 pk;
    pk[0] = (short)f2bf(lo.x); pk[1] = (short)f2bf(lo.y);
    pk[2] = (short)f2bf(lo.z); pk[3] = (short)f2bf(lo.w);
    pk[4] = (short)f2bf(hi.x); pk[5] = (short)f2bf(hi.y);
    pk[6] = (short)f2bf(hi.z); pk[7] = (short)f2bf(hi.w);
    *(bf16x8*)(&Wl[r * 128 + (c16 ^ (r & 7)) * 8]) = pk;
  }
  __syncthreads();

  f32x4 acc[4][4];
#pragma unroll
  for (int mi = 0; mi < 4; ++mi)
#pragma unroll
    for (int ni = 0; ni < 4; ++ni) acc[mi][ni] = (f32x4){0.f, 0.f, 0.f, 0.f};

#pragma unroll
  for (int ks = 0; ks < 4; ++ks) {
    bf16x8 af[4], bfr[4];
    int unit = (ks * 4 + quad) ^ (m & 7);
#pragma unroll
    for (int mi = 0; mi < 4; ++mi) {
      int row = (w & 1) * 64 + mi * 16 + m;
      af[mi] = *(const bf16x8*)(&Al[row * 128 + unit * 8]);
    }
#pragma unroll
    for (int ni = 0; ni < 4; ++ni) {
      int row = (w >> 1) * 64 + ni * 16 + m;
      bfr[ni] = *(const bf16x8*)(&Wl[row * 128 + unit * 8]);
    }
#pragma unroll
    for (int mi = 0; mi < 4; ++mi)
#pragma unroll
      for (int ni = 0; ni < 4; ++ni)
        acc[mi][ni] = __builtin_amdgcn_mfma_f32_16x16x32_bf16(
            af[mi], bfr[ni], acc[mi][ni], 0, 0, 0);
  }

#pragma unroll
  for (int ni = 0; ni < 4; ++ni) {
    int n = (w >> 1) * 64 + ni * 16 + m;
    float bp = bproj[n];
#pragma unroll
    for (int mi = 0; mi < 4; ++mi) {
      int trow = tau0 + (w & 1) * 64 + mi * 16 + quad * 4;
#pragma unroll
      for (int reg = 0; reg < 4; ++reg)
        out[(size_t)(trow + reg) * 128 + n] = acc[mi][ni][reg] + bp;
    }
  }
}

extern "C" void kernel_launch(void* const* d_in, const int* in_sizes, int n_in,
                              void* d_out, int out_size, void* d_ws, size_t ws_size,
                              hipStream_t stream) {
  (void)in_sizes; (void)n_in; (void)out_size; (void)ws_size;
  const float* x     = (const float*)d_in[0];
  const float* mask  = (const float*)d_in[1];
  const float* Wqkv  = (const float*)d_in[2];
  const float* bqkv  = (const float*)d_in[3];
  const float* Wqkv2 = (const float*)d_in[4];
  const float* bqkv2 = (const float*)d_in[5];
  const float* Wp1   = (const float*)d_in[6];
  const float* bp1   = (const float*)d_in[7];
  const float* Wp2   = (const float*)d_in[8];
  const float* bp2   = (const float*)d_in[9];
  const float* lq1   = (const float*)d_in[10];
  const float* lk1   = (const float*)d_in[11];
  const float* lq2   = (const float*)d_in[12];
  const float* lk2   = (const float*)d_in[13];
  const float* subln = (const float*)d_in[14];
  const float* Wproj = (const float*)d_in[15];
  const float* bproj = (const float*)d_in[16];
  float* out = (float*)d_out;

  float* pb = (float*)d_ws;                                               // 64 KB
  unsigned short* qkvws = (unsigned short*)((char*)d_ws + 65536);         // 251,658,240 B
  unsigned short* obuf  = (unsigned short*)((char*)d_ws + 65536 + 251658240); // 50,331,648 B

  hipLaunchKernelGGL(pb_kernel, dim3(16), dim3(256), 0, stream, Wp1, bp1, Wp2, bp2, pb);
  hipLaunchKernelGGL(qkv_proj, dim3(1536), dim3(256), 0, stream,
                     x, Wqkv, bqkv, Wqkv2, bqkv2, qkvws);
  hipLaunchKernelGGL(attn_core, dim3(3072), dim3(256), 0, stream,
                     qkvws, mask, pb, lq1, lk1, lq2, lk2, subln, obuf);
  hipLaunchKernelGGL(out_proj, dim3(1536), dim3(256), 0, stream,
                     obuf, Wproj, bproj, out);
}